// Round 13
// baseline (88.287 us; speedup 1.0000x reference)
//
#include <hip/hip_runtime.h>
#include <math.h>

// ---------------------------------------------------------------------------
// ScatteringNetwork:
//   img [8,1,256,256] f32, psi_re/psi_im [10,1,11,11] f32, blur_k [7,7] f32
//   out: concat([s0(1ch), s1_out(10ch), s2_out(100ch)]) at 32x32 -> [8, 111*1024]
//
// blur(conv(x,psi))[::8] == conv(x, psi (*) blur)[::8]; blur = g(x)g and
// psi_k = F_k (x) H_k (rank-1 exact) -> composed 17x17 kernel is rank-2:
// comb_k = F'r(x)H'r - F'i(x)H'i. Y==0/X==0 blur-pad clip -> F''/H''.
//
// R13 = R12 mega-fusion, implementation rebuilt:
//  - x-halved blocks: LDS 38.5 KB -> 4 blocks/CU x 6 waves = 24 waves (75%)
//  - div-free incremental (r,t) task loops (R12 had magic-mul div per iter)
//  - padded img (288x288, border 16) in ws -> staging = aligned float4, no
//    predicates in hot path
//  - C as re/im planes, t'=t+(t>>3) swizzle + k*328 plane offset -> <=2-way
//    banks (R12 out-phase was 16-way, 800K conflicts)
//
// ws: [0) pimg 8*288*288 ; [663552) fhp 10*136
// fhp per ch: [0)H'r [17)H'i [34)H''r [51)H''i [68)F'r [85)F'i [102)F''r [119)F''i
// ---------------------------------------------------------------------------

#define PIMG_SZ (288 * 288)
#define FHP_OFF (8 * PIMG_SZ)

// ---------------- k_prep: padded img copy + factor table -------------------
__global__ __launch_bounds__(256) void k_prep(const float* __restrict__ img,
                                              const float* __restrict__ psi_re,
                                              const float* __restrict__ psi_im,
                                              const float* __restrict__ blur,
                                              float* __restrict__ pimg,
                                              float* __restrict__ fhp) {
    int bid = blockIdx.x, tid = threadIdx.x;
    if (bid < 288) {                  // pimg: 8 n x 36 rowgroups x 8 rows
        int n = bid / 36, rg = bid - n * 36;
        float* dst = pimg + n * PIMG_SZ + rg * 8 * 288;
        const float* src = img + n * 65536;
        for (int i = tid; i < 576; i += 256) {
            int lr = i / 72, c4 = i - lr * 72;
            int prow = rg * 8 + lr;
            int irow = prow - 16;
            float4 v = {0.f, 0.f, 0.f, 0.f};
            if (irow >= 0 && irow < 256 && c4 >= 4 && c4 < 68)
                v = *(const float4*)(src + irow * 256 + 4 * c4 - 16);
            *(float4*)(dst + lr * 288 + 4 * c4) = v;
        }
        return;
    }
    // fhp (validated R6-R12)
    for (int g = tid; g < 1360; g += 256) {
        int ch = g / 136;
        int w = g - ch * 136;
        int part = w / 17;
        int i = w - part * 17;
        const float* pr = psi_re + ch * 121;
        const float* pi = psi_im + ch * 121;
        float val = 0.f;
        if (part < 4) {                       // H-type: H_j = psi[5][j]
            int qmin = (part >= 2) ? 3 : 0;
            int comp = part & 1;
            float bden = blur[24];
            for (int q = qmin; q < 7; ++q) {
                int jj = i - q;
                if (jj < 0 || jj > 10) continue;
                float bq = blur[21 + q] / bden;
                float hh = comp ? pi[55 + jj] : pr[55 + jj];
                val += bq * hh;
            }
        } else {                              // F-type: F_i = psi[i][5]/psi[5][5]
            int pmin = (part >= 6) ? 3 : 0;
            int comp = part & 1;
            float dr = pr[60], di = pi[60];
            float inv = 1.f / (dr * dr + di * di);
            for (int p = pmin; p < 7; ++p) {
                int ii = i - p;
                if (ii < 0 || ii > 10) continue;
                float ap = blur[p * 7 + 3];
                float nr = pr[ii * 11 + 5], ni = pi[ii * 11 + 5];
                float f = comp ? (ni * dr - nr * di) * inv
                               : (nr * dr + ni * di) * inv;
                val += ap * f;
            }
        }
        fhp[g] = val;
    }
}

// ---------------- k_fused2: one block per (Y, x-half, src, n) --------------
// 384 threads. bufA: strip [27][160] (4320 f) / s1 [17][160] overlay.
// bufB: Iv [17][156][2] (5304 f) / C planes (10*328=3280) overlay.
__global__ __launch_bounds__(384, 6) void k_fused2(const float* __restrict__ pimg,
                                                   const float* __restrict__ psi_re,
                                                   const float* __restrict__ psi_im,
                                                   const float* __restrict__ blur,
                                                   const float* __restrict__ fhp,
                                                   float* __restrict__ out) {
    __shared__ __align__(16) float bufA[4320];
    __shared__ __align__(16) float bufB[5304];
    const int tid = threadIdx.x;
    const int Y = blockIdx.x >> 1;
    const int h = blockIdx.x & 1;
    const int x0 = 128 * h;
    const int src = blockIdx.y;   // 0..10
    const int n = blockIdx.z;
    size_t nb = (size_t)n * 111 * 1024;

    if (src == 0) {
        // ---- s0 + s1_out: strip [17][160] = img rows 8Y-8.., cols x0-16..
        {
            const float* gp = pimg + n * PIMG_SZ + (8 * Y + 8) * 288 + x0;
            int r = tid / 40, c4 = tid - (tid / 40) * 40;
            while (r < 17) {
                *(float4*)(bufA + r * 160 + 4 * c4) = *(const float4*)(gp + r * 288 + 4 * c4);
                r += 9; c4 += 24;
                if (c4 >= 40) { c4 -= 40; ++r; }
            }
        }
        __syncthreads();
        if (tid < 137) {          // C_k(t) = sum_i F'_k(i) * strip(i, t+8)
            int t = tid;
            float v[17];
#pragma unroll
            for (int i = 0; i < 17; ++i) v[i] = bufA[i * 160 + t + 8];
            int tp = t + (t >> 3);
#pragma unroll
            for (int k = 0; k < 10; ++k) {
                const float* fR = fhp + k * 136 + ((Y == 0) ? 102 : 68);  // s_load
                const float* fI = fhp + k * 136 + ((Y == 0) ? 119 : 85);
                float cr = 0.f, ci = 0.f;
#pragma unroll
                for (int i = 0; i < 17; ++i) {
                    cr = fmaf(fR[i], v[i], cr);
                    ci = fmaf(fI[i], v[i], ci);
                }
                bufB[k * 328 + tp] = cr;
                bufB[k * 328 + 164 + tp] = ci;
            }
        } else if (tid >= 352 && tid < 368) {   // s0: clipped 7x7 blur
            int X = tid - 352;
            float s0 = 0.f;
#pragma unroll
            for (int p = 0; p < 7; ++p)
#pragma unroll
                for (int q = 0; q < 7; ++q)
                    s0 = fmaf(blur[p * 7 + q], bufA[(p + 5) * 160 + 8 * X + q + 13], s0);
            out[nb + Y * 32 + 16 * h + X] = s0;
        }
        __syncthreads();
        if (tid < 160) {          // out: 10 k x 16 X
            int k = tid >> 4, X = tid & 15;
            const float* hb = fhp + k * 136 + ((h == 0 && X == 0) ? 34 : 0);
            float acc = 0.f;
#pragma unroll
            for (int j = 0; j < 17; ++j) {
                int t = 8 * X + j, tp = t + (t >> 3);
                acc = fmaf(hb[j], bufB[k * 328 + tp], acc);
                acc = fmaf(-hb[17 + j], bufB[k * 328 + 164 + tp], acc);
            }
            out[nb + (size_t)(1 + k) * 1024 + Y * 32 + 16 * h + X] = acc;
        }
        return;
    }

    // ---- s2 path, group g = src-1 ----
    int g = src - 1;
    const float* pr = psi_re + g * 121;   // block-uniform -> s_load weights
    const float* pi = psi_im + g * 121;
    float dr = pr[60], di = pi[60];
    float inv = rsqrtf(dr * dr + di * di);

    // stage strip [27][160] = img rows 8Y-13.., cols x0-16.. (padded, no preds)
    {
        const float* gp = pimg + n * PIMG_SZ + (8 * Y + 3) * 288 + x0;
        int r = tid / 40, c4 = tid - (tid / 40) * 40;
        while (r < 27) {
            *(float4*)(bufA + r * 160 + 4 * c4) = *(const float4*)(gp + r * 288 + 4 * c4);
            r += 9; c4 += 24;
            if (c4 >= 40) { c4 -= 40; ++r; }
        }
    }
    __syncthreads();

    // Iv(r,v) = sum_p F_p * strip(r+p, v+3)  (17 x 154 complex)
    {
        int r = tid / 154, v = tid - (tid / 154) * 154;
        while (r < 17) {
            const float* sb = bufA + r * 160 + v + 3;
            float ar = 0.f, ai = 0.f;
#pragma unroll
            for (int p = 0; p < 11; ++p) {
                float x = sb[p * 160];
                ar = fmaf(pr[p * 11 + 5], x, ar);
                ai = fmaf(pi[p * 11 + 5], x, ai);
            }
            float* d = bufB + (r * 156 + v) * 2;
            d[0] = ar; d[1] = ai;
            r += 2; v += 76;
            if (v >= 154) { v -= 154; ++r; }
        }
    }
    __syncthreads();

    // s1(r,t) = inv*|sum_j H_j Iv(r,t+j)|  (17 x 144, overlay strip)
    {
        int rowbase = 8 * Y - 8;
        int r = tid / 144, t = tid - (tid / 144) * 144;
        while (r < 17) {
            int ry = rowbase + r;
            int gx = x0 + t - 8;
            float val = 0.f;
            if (ry >= 0 && ry < 256 && gx >= 0 && gx < 256) {
                const float* ivp = bufB + (r * 156 + t) * 2;
                float sr = 0.f, si = 0.f;
#pragma unroll
                for (int j = 0; j < 11; ++j) {
                    float hr = pr[55 + j], hi2 = pi[55 + j];
                    float vr = ivp[2 * j], vi2 = ivp[2 * j + 1];
                    sr = fmaf(hr, vr, fmaf(-hi2, vi2, sr));
                    si = fmaf(hr, vi2, fmaf(hi2, vr, si));
                }
                val = inv * sqrtf(fmaf(sr, sr, si * si));
            }
            bufA[r * 160 + t] = val;
            r += 2; t += 96;
            if (t >= 144) { t -= 144; ++r; }
        }
    }
    __syncthreads();

    // C_k(t) = sum_i F'_k(i) s1(i,t)  (re/im planes, swizzled, overlay Iv)
    if (tid < 137) {
        int t = tid;
        float v[17];
#pragma unroll
        for (int i = 0; i < 17; ++i) v[i] = bufA[i * 160 + t];
        int tp = t + (t >> 3);
#pragma unroll
        for (int k = 0; k < 10; ++k) {
            const float* fR = fhp + k * 136 + ((Y == 0) ? 102 : 68);  // s_load
            const float* fI = fhp + k * 136 + ((Y == 0) ? 119 : 85);
            float cr = 0.f, ci = 0.f;
#pragma unroll
            for (int i = 0; i < 17; ++i) {
                cr = fmaf(fR[i], v[i], cr);
                ci = fmaf(fI[i], v[i], ci);
            }
            bufB[k * 328 + tp] = cr;
            bufB[k * 328 + 164 + tp] = ci;
        }
    }
    __syncthreads();

    // out(k,X) = sum_j [H'r(j) Cr(8X+j) - H'i(j) Ci(8X+j)]
    if (tid < 160) {
        int k = tid >> 4, X = tid & 15;
        const float* hb = fhp + k * 136 + ((h == 0 && X == 0) ? 34 : 0);
        float acc = 0.f;
#pragma unroll
        for (int j = 0; j < 17; ++j) {
            int t = 8 * X + j, tp = t + (t >> 3);
            acc = fmaf(hb[j], bufB[k * 328 + tp], acc);
            acc = fmaf(-hb[17 + j], bufB[k * 328 + 164 + tp], acc);
        }
        out[nb + (size_t)(11 + g * 10 + k) * 1024 + Y * 32 + 16 * h + X] = acc;
    }
}

extern "C" void kernel_launch(void* const* d_in, const int* in_sizes, int n_in,
                              void* d_out, int out_size, void* d_ws, size_t ws_size,
                              hipStream_t stream) {
    const float* img    = (const float*)d_in[0];
    const float* psi_re = (const float*)d_in[1];
    const float* psi_im = (const float*)d_in[2];
    const float* blur   = (const float*)d_in[3];
    float* out = (float*)d_out;
    float* ws = (float*)d_ws;
    float* pimg = ws;
    float* fhp  = ws + FHP_OFF;

    k_prep<<<289, 256, 0, stream>>>(img, psi_re, psi_im, blur, pimg, fhp);

    dim3 g2(64, 11, 8);
    k_fused2<<<g2, 384, 0, stream>>>(pimg, psi_re, psi_im, blur, fhp, out);
}

// Round 14
// 78.265 us; speedup vs baseline: 1.1281x; 1.1281x over previous
//
#include <hip/hip_runtime.h>
#include <math.h>

// ---------------------------------------------------------------------------
// ScatteringNetwork:
//   img [8,1,256,256] f32, psi_re/psi_im [10,1,11,11] f32, blur_k [7,7] f32
//   out: concat([s0(1ch), s1_out(10ch), s2_out(100ch)]) at 32x32 -> [8, 111*1024]
//
// blur(conv(x,psi))[::8] == conv(x, psi (*) blur)[::8]; blur = g(x)g and
// psi_k = F_k (x) H_k (rank-1 exact) -> composed 17x17 kernel is rank-2:
// comb_k = F'r(x)H'r - F'i(x)H'i. Y==0/X==0 blur-pad clip -> F''/H''.
//
// R14: fused per-(Y,src,n) block, phases rebuilt for FMA density:
//  - Iv transposed (lane=col, 8 rows/thread): conflict-free strip reads
//  - Iv & s1 & C stored as re/im planes with idx = x+(x>>3) swizzle: all
//    stride-8 consumers become stride-9 (32 distinct banks)
//  - s1 sliding-window 8-wide: 36 reads / 352 FMA
//  - C phase kh wave-uniform (readfirstlane) -> weights stay s_load
//  - s0 path shares C/out code with s2 (identical composed-conv indexing)
//
// ws: [0) pimg 8*288*288 (border 16, zero) ; [663552) fhp 10*136
// fhp per ch: [0)H'r [17)H'i [34)H''r [51)H''i [68)F'r [85)F'i [102)F''r [119)F''i
// ---------------------------------------------------------------------------

#define PIMG_SZ (288 * 288)
#define FHP_OFF (8 * PIMG_SZ)
#define SSTR  284            // strip row stride (27 rows)
#define W1    308            // s1 / s0 swizzled row stride (17 rows)
#define IVSTR 308            // Iv plane row stride
#define IVPL  (17 * 308)     // Iv plane size (re at 0, im at IVPL)
#define CSTR  600            // C per-k stride (re at 0, im at +300)

// ---------------- k_prep: padded img copy + factor table (R13, proven) -----
__global__ __launch_bounds__(256) void k_prep(const float* __restrict__ img,
                                              const float* __restrict__ psi_re,
                                              const float* __restrict__ psi_im,
                                              const float* __restrict__ blur,
                                              float* __restrict__ pimg,
                                              float* __restrict__ fhp) {
    int bid = blockIdx.x, tid = threadIdx.x;
    if (bid < 288) {                  // pimg: 8 n x 36 rowgroups x 8 rows
        int n = bid / 36, rg = bid - n * 36;
        float* dst = pimg + n * PIMG_SZ + rg * 8 * 288;
        const float* src = img + n * 65536;
        for (int i = tid; i < 576; i += 256) {
            int lr = i / 72, c4 = i - lr * 72;
            int prow = rg * 8 + lr;
            int irow = prow - 16;
            float4 v = {0.f, 0.f, 0.f, 0.f};
            if (irow >= 0 && irow < 256 && c4 >= 4 && c4 < 68)
                v = *(const float4*)(src + irow * 256 + 4 * c4 - 16);
            *(float4*)(dst + lr * 288 + 4 * c4) = v;
        }
        return;
    }
    for (int g = tid; g < 1360; g += 256) {
        int ch = g / 136;
        int w = g - ch * 136;
        int part = w / 17;
        int i = w - part * 17;
        const float* pr = psi_re + ch * 121;
        const float* pi = psi_im + ch * 121;
        float val = 0.f;
        if (part < 4) {                       // H-type
            int qmin = (part >= 2) ? 3 : 0;
            int comp = part & 1;
            float bden = blur[24];
            for (int q = qmin; q < 7; ++q) {
                int jj = i - q;
                if (jj < 0 || jj > 10) continue;
                float bq = blur[21 + q] / bden;
                float hh = comp ? pi[55 + jj] : pr[55 + jj];
                val += bq * hh;
            }
        } else {                              // F-type
            int pmin = (part >= 6) ? 3 : 0;
            int comp = part & 1;
            float dr = pr[60], di = pi[60];
            float inv = 1.f / (dr * dr + di * di);
            for (int p = pmin; p < 7; ++p) {
                int ii = i - p;
                if (ii < 0 || ii > 10) continue;
                float ap = blur[p * 7 + 3];
                float nr = pr[ii * 11 + 5], ni = pi[ii * 11 + 5];
                float f = comp ? (ni * dr - nr * di) * inv
                               : (nr * dr + ni * di) * inv;
                val += ap * f;
            }
        }
        fhp[g] = val;
    }
}

// ---------------- k_fused3: one block per (Y, src, n), 512 thr -------------
__global__ __launch_bounds__(512, 4) void k_fused3(const float* __restrict__ pimg,
                                                   const float* __restrict__ psi_re,
                                                   const float* __restrict__ psi_im,
                                                   const float* __restrict__ blur,
                                                   const float* __restrict__ fhp,
                                                   float* __restrict__ out) {
    __shared__ __align__(16) float bufA[7668];    // strip [27][284] / s1 [17][308]
    __shared__ __align__(16) float bufB[10472];   // Iv planes / C planes overlay
    const int tid = threadIdx.x;
    const int lane = tid & 63;
    const int wave = tid >> 6;
    const int Y = blockIdx.x;
    const int src = blockIdx.y;
    const int n = blockIdx.z;
    size_t nb = (size_t)n * 111 * 1024;

    if (src == 0) {
        // ---- stage s0/s1 strip: 17 rows x 272 cols (img rows 8Y-8..),
        // swizzled scalar writes into the [17][308] layout C expects
        const float* gp = pimg + n * PIMG_SZ + (8 * Y + 8) * 288 + 8;
        for (int idx = tid; idx < 17 * 68; idx += 512) {
            int r = idx / 68, c4 = idx - r * 68;
            float4 v = *(const float4*)(gp + r * 288 + 4 * c4);
            int c = 4 * c4;
            int d = r * W1 + c + (c >> 3);   // (c>>3) constant within a float4
            bufA[d] = v.x; bufA[d + 1] = v.y; bufA[d + 2] = v.z; bufA[d + 3] = v.w;
        }
    } else {
        // ---- s2 path: group g = src-1 ----
        int g = src - 1;
        const float* pr = psi_re + g * 121;   // block-uniform -> s_load
        const float* pi = psi_im + g * 121;
        float dr = pr[60], di = pi[60];
        float inv = rsqrtf(dr * dr + di * di);

        // stage strip [27][284]: img rows 8Y-13.., cols -8..263 (float4)
        const float* gp = pimg + n * PIMG_SZ + (8 * Y + 3) * 288 + 8;
        for (int idx = tid; idx < 27 * 68; idx += 512) {
            int r = idx / 68, c4 = idx - r * 68;
            *(float4*)(bufA + r * SSTR + 4 * c4) = *(const float4*)(gp + r * 288 + 4 * c4);
        }
        __syncthreads();

        // Iv: lane = one v (0..265), 8 rows per task; conflict-free reads
        for (int task = tid; task < 532; task += 512) {
            int rg = (task >= 266) ? 1 : 0;
            int v = task - rg * 266;
            int r0 = rg * 8;
            const float* sp = bufA + r0 * SSTR + v + 3;
            float xv[18];
#pragma unroll
            for (int p = 0; p < 18; ++p) xv[p] = sp[p * SSTR];
            int dsw = v + (v >> 3);
            float* dR = bufB + r0 * IVSTR + dsw;
#pragma unroll
            for (int m = 0; m < 8; ++m) {
                float ar = 0.f, ai = 0.f;
#pragma unroll
                for (int p = 0; p < 11; ++p) {
                    ar = fmaf(pr[p * 11 + 5], xv[m + p], ar);
                    ai = fmaf(pi[p * 11 + 5], xv[m + p], ai);
                }
                dR[m * IVSTR] = ar;
                dR[m * IVSTR + IVPL] = ai;
            }
        }
        if (tid < 266) {                     // row r = 16
            int v = tid;
            const float* sp = bufA + 16 * SSTR + v + 3;
            float ar = 0.f, ai = 0.f;
#pragma unroll
            for (int p = 0; p < 11; ++p) {
                float x = sp[p * SSTR];
                ar = fmaf(pr[p * 11 + 5], x, ar);
                ai = fmaf(pi[p * 11 + 5], x, ai);
            }
            int dsw = v + (v >> 3);
            bufB[16 * IVSTR + dsw] = ar;
            bufB[16 * IVSTR + IVPL + dsw] = ai;
        }
        __syncthreads();

        // s1: thread = (r, 8-col group); sliding window, swizzled R/I reads
        int rowbase = 8 * Y - 8;
        for (int t2 = tid; t2 < 544; t2 += 512) {
            int r = t2 >> 5, xg = t2 & 31;   // cs = 8xg+8 .. +7, x = cs-8
            int ry = rowbase + r;
            int wb = r * W1 + 9 * xg + 9;    // idx(cs)=cs+(cs>>3), cs=8xg+8+m
            if (ry >= 0 && ry < 256) {
                const float* sR = bufB + r * IVSTR + 9 * xg;
                float xr[18], xi[18];
#pragma unroll
                for (int j = 0; j < 18; ++j) {
                    int off = j + (j >> 3);  // idx(x0+j) = 9xg + j + (j>>3)
                    xr[j] = sR[off];
                    xi[j] = sR[off + IVPL];
                }
#pragma unroll
                for (int m = 0; m < 8; ++m) {
                    float sr = 0.f, si = 0.f;
#pragma unroll
                    for (int j = 0; j < 11; ++j) {
                        float hr = pr[55 + j], hi2 = pi[55 + j];
                        sr = fmaf(hr, xr[m + j], fmaf(-hi2, xi[m + j], sr));
                        si = fmaf(hr, xi[m + j], fmaf(hi2, xr[m + j], si));
                    }
                    bufA[wb + m] = inv * sqrtf(fmaf(sr, sr, si * si));
                }
            } else {
#pragma unroll
                for (int m = 0; m < 8; ++m) bufA[wb + m] = 0.f;
            }
        }
        if (tid < 17) {                      // edge zeros cs 0..7
            int r = tid;
#pragma unroll
            for (int cs = 0; cs < 8; ++cs) bufA[r * W1 + cs] = 0.f;
        } else if (tid < 34) {               // edge zeros cs 264..271
            int r = tid - 17;
#pragma unroll
            for (int m = 0; m < 8; ++m) {
                int cs = 264 + m;
                bufA[r * W1 + cs + (cs >> 3)] = 0.f;
            }
        }
    }
    __syncthreads();

    // ---- C phase (common): C_k(t) = sum_i F'_k(i) * bufA(i, t), t 0..264 ----
    {
        int kh = __builtin_amdgcn_readfirstlane((wave >= 4) ? 1 : 0);
        int fro = (Y == 0) ? 102 : 68;
        int fio = (Y == 0) ? 119 : 85;
        auto compute_C = [&](int t) {
            int tsw = t + (t >> 3);
            float v[17];
#pragma unroll
            for (int i = 0; i < 17; ++i) v[i] = bufA[i * W1 + tsw];
#pragma unroll
            for (int kk = 0; kk < 5; ++kk) {
                int k = kh * 5 + kk;
                const float* fR = fhp + k * 136 + fro;   // uniform -> s_load
                const float* fI = fhp + k * 136 + fio;
                float cr = 0.f, ci = 0.f;
#pragma unroll
                for (int i = 0; i < 17; ++i) {
                    cr = fmaf(fR[i], v[i], cr);
                    ci = fmaf(fI[i], v[i], ci);
                }
                bufB[k * CSTR + tsw] = cr;
                bufB[k * CSTR + 300 + tsw] = ci;
            }
        };
        compute_C(((wave & 3) << 6) + lane);             // t 0..255
        if (lane < 9 && (wave == 0 || wave == 4))
            compute_C(256 + lane);                       // t 256..264
    }
    __syncthreads();

    // ---- out phase (common) ----
    int ch0 = (src == 0) ? 1 : 11 + (src - 1) * 10;
    if (tid < 320) {
        int k = tid >> 5, X = tid & 31;
        const float* hb = fhp + k * 136 + ((X == 0) ? 34 : 0);
        const float* cR = bufB + k * CSTR + 9 * X;       // tp(8X+j)=9X+j+(j>>3)
        float acc = 0.f;
#pragma unroll
        for (int j = 0; j < 17; ++j) {
            int off = j + (j >> 3);
            acc = fmaf(hb[j], cR[off], acc);
            acc = fmaf(-hb[17 + j], cR[off + 300], acc);
        }
        out[nb + (size_t)(ch0 + k) * 1024 + Y * 32 + X] = acc;
    } else if (src == 0 && tid < 352) {                  // s0: clipped blur
        int X = tid - 320;
        float s0 = 0.f;
#pragma unroll
        for (int p = 0; p < 7; ++p)
#pragma unroll
            for (int q = 0; q < 7; ++q) {
                int c = 8 * X + q + 5;
                s0 = fmaf(blur[p * 7 + q], bufA[(p + 5) * W1 + c + (c >> 3)], s0);
            }
        out[nb + Y * 32 + X] = s0;
    }
}

extern "C" void kernel_launch(void* const* d_in, const int* in_sizes, int n_in,
                              void* d_out, int out_size, void* d_ws, size_t ws_size,
                              hipStream_t stream) {
    const float* img    = (const float*)d_in[0];
    const float* psi_re = (const float*)d_in[1];
    const float* psi_im = (const float*)d_in[2];
    const float* blur   = (const float*)d_in[3];
    float* out = (float*)d_out;
    float* ws = (float*)d_ws;
    float* pimg = ws;
    float* fhp  = ws + FHP_OFF;

    k_prep<<<289, 256, 0, stream>>>(img, psi_re, psi_im, blur, pimg, fhp);

    dim3 g2(32, 11, 8);
    k_fused3<<<g2, 512, 0, stream>>>(pimg, psi_re, psi_im, blur, fhp, out);
}

// Round 15
// 61.260 us; speedup vs baseline: 1.4412x; 1.2776x over previous
//
#include <hip/hip_runtime.h>
#include <math.h>

// ---------------------------------------------------------------------------
// ScatteringNetwork — fused, rank-2 composed conv + theta-symmetry.
//
// psi_k = F_k (x) H_k (rank-1). theta = pi*k/5: sin(th3)=sin(th2),
// cos(th3)=-cos(th2) -> H3=H2, F3=conj(F2) (pairs (1,4),(2,3),(6,9),(7,8);
// k0,k5 have Hi==0). Exploited three ways:
//  - s1 pair blocks: Iv_b = conj(Iv_a) free; both s1 channels from 4 shared
//    real convs: s1a=|(a-b)+i(c+d)|, s1b=|(a+b)+i(c-d)|
//  - C phase: C_conj = conj(C) -> only 6 distinct k planes {0,1,2,5,6,7}
//  - out phase: u=H'r*Cr, v=H'i*Ci -> out_k=u-v, out_partner=u+v
// Grid y: 7 = img, g0, g5, pair(1,4), pair(2,3), pair(6,9), pair(7,8).
//
// ws: [0) pimg 8*288*288 (border 16, zero) ; [663552) fhp 10*136
// fhp per ch: [0)H'r [17)H'i [34)H''r [51)H''i [68)F'r [85)F'i [102)F''r [119)F''i
// ---------------------------------------------------------------------------

#define PIMG_SZ (288 * 288)
#define FHP_OFF (8 * PIMG_SZ)
#define SSTR  284            // strip row stride (27 rows)
#define W1    298            // s1 swizzled row stride (t 0..264 -> tsw 0..297)
#define S1SZ  (17 * 298)     // 5066, per-channel s1 region
#define IVSTR 300            // Iv plane row stride
#define IVPL  (17 * 300)     // 5100
#define CSTR  600            // C per-plane stride (re@0, im@300)

// ---------------- k_prep: padded img copy + factor table (proven) ----------
__global__ __launch_bounds__(256) void k_prep(const float* __restrict__ img,
                                              const float* __restrict__ psi_re,
                                              const float* __restrict__ psi_im,
                                              const float* __restrict__ blur,
                                              float* __restrict__ pimg,
                                              float* __restrict__ fhp) {
    int bid = blockIdx.x, tid = threadIdx.x;
    if (bid < 288) {
        int n = bid / 36, rg = bid - n * 36;
        float* dst = pimg + n * PIMG_SZ + rg * 8 * 288;
        const float* src = img + n * 65536;
        for (int i = tid; i < 576; i += 256) {
            int lr = i / 72, c4 = i - lr * 72;
            int prow = rg * 8 + lr;
            int irow = prow - 16;
            float4 v = {0.f, 0.f, 0.f, 0.f};
            if (irow >= 0 && irow < 256 && c4 >= 4 && c4 < 68)
                v = *(const float4*)(src + irow * 256 + 4 * c4 - 16);
            *(float4*)(dst + lr * 288 + 4 * c4) = v;
        }
        return;
    }
    for (int g = tid; g < 1360; g += 256) {
        int ch = g / 136;
        int w = g - ch * 136;
        int part = w / 17;
        int i = w - part * 17;
        const float* pr = psi_re + ch * 121;
        const float* pi = psi_im + ch * 121;
        float val = 0.f;
        if (part < 4) {                       // H-type
            int qmin = (part >= 2) ? 3 : 0;
            int comp = part & 1;
            float bden = blur[24];
            for (int q = qmin; q < 7; ++q) {
                int jj = i - q;
                if (jj < 0 || jj > 10) continue;
                float bq = blur[21 + q] / bden;
                float hh = comp ? pi[55 + jj] : pr[55 + jj];
                val += bq * hh;
            }
        } else {                              // F-type
            int pmin = (part >= 6) ? 3 : 0;
            int comp = part & 1;
            float dr = pr[60], di = pi[60];
            float inv = 1.f / (dr * dr + di * di);
            for (int p = pmin; p < 7; ++p) {
                int ii = i - p;
                if (ii < 0 || ii > 10) continue;
                float ap = blur[p * 7 + 3];
                float nr = pr[ii * 11 + 5], ni = pi[ii * 11 + 5];
                float f = comp ? (ni * dr - nr * di) * inv
                               : (nr * dr + ni * di) * inv;
                val += ap * f;
            }
        }
        fhp[g] = val;
    }
}

// ---------------- k_fused4: one block per (Y, src2, n), 512 thr ------------
__global__ __launch_bounds__(512, 4) void k_fused4(const float* __restrict__ pimg,
                                                   const float* __restrict__ psi_re,
                                                   const float* __restrict__ psi_im,
                                                   const float* __restrict__ blur,
                                                   const float* __restrict__ fhp,
                                                   float* __restrict__ out) {
    __shared__ __align__(16) float bufA[10132];   // strip / s1a+s1b
    __shared__ __align__(16) float bufB[10200];   // Iv planes / C planes
    const int tid = threadIdx.x;
    const int lane = tid & 63;
    const int wave = tid >> 6;
    const int Y = blockIdx.x;
    const int src2 = blockIdx.y;    // 0 img, 1 g0, 2 g5, 3..6 pairs
    const int n = blockIdx.z;
    size_t nb = (size_t)n * 111 * 1024;

    const bool isimg = (src2 == 0);
    const bool paired = (src2 >= 3);
    int ga = 0, gb = 0;
    if (src2 == 1) ga = gb = 0;
    else if (src2 == 2) ga = gb = 5;
    else if (paired) {
        int p2 = src2 - 3;
        ga = (p2 < 2) ? 1 + p2 : 4 + p2;      // 1,2,6,7
        gb = (p2 < 2) ? 4 - p2 : 11 - p2;     // 4,3,9,8
    }

    if (isimg) {
        // stage img strip [17 rows] swizzled into W1 layout (zeros from pimg pad)
        const float* gp = pimg + n * PIMG_SZ + (8 * Y + 8) * 288 + 8;
        for (int idx = tid; idx < 17 * 68; idx += 512) {
            int r = idx / 68, c4 = idx - r * 68;
            float4 v = *(const float4*)(gp + r * 288 + 4 * c4);
            int c = 4 * c4;
            int d = r * W1 + c + (c >> 3);
            bufA[d] = v.x; bufA[d + 1] = v.y; bufA[d + 2] = v.z; bufA[d + 3] = v.w;
        }
    } else {
        const float* pr = psi_re + ga * 121;   // block-uniform -> s_load
        const float* pi = psi_im + ga * 121;
        float dr = pr[60], di = pi[60];
        float inv = rsqrtf(dr * dr + di * di);

        // stage strip [27][284]
        const float* gp = pimg + n * PIMG_SZ + (8 * Y + 3) * 288 + 8;
        for (int idx = tid; idx < 27 * 68; idx += 512) {
            int r = idx / 68, c4 = idx - r * 68;
            *(float4*)(bufA + r * SSTR + 4 * c4) = *(const float4*)(gp + r * 288 + 4 * c4);
        }
        __syncthreads();

        // Iv: lane = col v, 8 rows/task (conflict-free strip reads)
        for (int task = tid; task < 532; task += 512) {
            int rg = (task >= 266) ? 1 : 0;
            int v = task - rg * 266;
            int r0 = rg * 8;
            const float* sp = bufA + r0 * SSTR + v + 3;
            float xv[18];
#pragma unroll
            for (int p = 0; p < 18; ++p) xv[p] = sp[p * SSTR];
            int dsw = v + (v >> 3);
            float* dR = bufB + r0 * IVSTR + dsw;
#pragma unroll
            for (int m = 0; m < 8; ++m) {
                float ar = 0.f, ai = 0.f;
#pragma unroll
                for (int p = 0; p < 11; ++p) {
                    ar = fmaf(pr[p * 11 + 5], xv[m + p], ar);
                    ai = fmaf(pi[p * 11 + 5], xv[m + p], ai);
                }
                dR[m * IVSTR] = ar;
                dR[m * IVSTR + IVPL] = ai;
            }
        }
        if (tid < 266) {
            int v = tid;
            const float* sp = bufA + 16 * SSTR + v + 3;
            float ar = 0.f, ai = 0.f;
#pragma unroll
            for (int p = 0; p < 11; ++p) {
                float x = sp[p * SSTR];
                ar = fmaf(pr[p * 11 + 5], x, ar);
                ai = fmaf(pi[p * 11 + 5], x, ai);
            }
            int dsw = v + (v >> 3);
            bufB[16 * IVSTR + dsw] = ar;
            bufB[16 * IVSTR + IVPL + dsw] = ai;
        }
        __syncthreads();

        // s1: tasks (r, 8-col group). paired -> 4 shared real convs, 2 outputs
        int rowbase = 8 * Y - 8;
        for (int t2 = tid; t2 < 544; t2 += 512) {
            int r = t2 >> 5, xg = t2 & 31;
            int ry = rowbase + r;
            int wb = r * W1 + 9 * xg + 9;
            if (ry >= 0 && ry < 256) {
                const float* sR = bufB + r * IVSTR + 9 * xg;
                float xr[18], xi[18];
#pragma unroll
                for (int j = 0; j < 18; ++j) {
                    int off = j + (j >> 3);
                    xr[j] = sR[off];
                    xi[j] = sR[off + IVPL];
                }
                if (paired) {
#pragma unroll
                    for (int m = 0; m < 8; ++m) {
                        float a = 0.f, b = 0.f, c = 0.f, d = 0.f;
#pragma unroll
                        for (int j = 0; j < 11; ++j) {
                            float hr = pr[55 + j], hi2 = pi[55 + j];
                            a = fmaf(hr, xr[m + j], a);
                            b = fmaf(hi2, xi[m + j], b);
                            c = fmaf(hr, xi[m + j], c);
                            d = fmaf(hi2, xr[m + j], d);
                        }
                        float e1 = a - b, o1 = c + d;
                        float e2 = a + b, o2 = c - d;
                        bufA[wb + m]        = inv * sqrtf(fmaf(e1, e1, o1 * o1));
                        bufA[S1SZ + wb + m] = inv * sqrtf(fmaf(e2, e2, o2 * o2));
                    }
                } else {
#pragma unroll
                    for (int m = 0; m < 8; ++m) {
                        float sr = 0.f, si = 0.f;
#pragma unroll
                        for (int j = 0; j < 11; ++j) {
                            float hr = pr[55 + j], hi2 = pi[55 + j];
                            sr = fmaf(hr, xr[m + j], fmaf(-hi2, xi[m + j], sr));
                            si = fmaf(hr, xi[m + j], fmaf(hi2, xr[m + j], si));
                        }
                        bufA[wb + m] = inv * sqrtf(fmaf(sr, sr, si * si));
                    }
                }
            } else {
#pragma unroll
                for (int m = 0; m < 8; ++m) {
                    bufA[wb + m] = 0.f;
                    if (paired) bufA[S1SZ + wb + m] = 0.f;
                }
            }
        }
        if (tid < 17) {                      // edge zeros: t 0..7 and t 264
            int r = tid;
#pragma unroll
            for (int t = 0; t < 8; ++t) {
                bufA[r * W1 + t] = 0.f;
                if (paired) bufA[S1SZ + r * W1 + t] = 0.f;
            }
            bufA[r * W1 + 297] = 0.f;
            if (paired) bufA[S1SZ + r * W1 + 297] = 0.f;
        }
    }
    __syncthreads();

    // ---- C phase: 6 distinct k (conj-trick); paired: kh selects channel ----
    {
        int kh = __builtin_amdgcn_readfirstlane(wave >> 2);   // 0 or 1
        int fro = (Y == 0) ? 102 : 68;
        int fio = (Y == 0) ? 119 : 85;
        const float* s1base = bufA + (paired ? kh * S1SZ : 0);
        auto doC = [&](int t) {
            int tsw = t + (t >> 3);
            float v[17];
#pragma unroll
            for (int i = 0; i < 17; ++i) v[i] = s1base[i * W1 + tsw];
            int nk = paired ? 6 : 3;
            for (int kk = 0; kk < nk; ++kk) {     // block/wave-uniform bound
                int k, p;
                if (paired) { k = (kk < 3) ? kk : kk + 2; p = kh * 6 + kk; }
                else        { k = kh * 5 + kk;            p = kh * 3 + kk; }
                const float* fR = fhp + k * 136 + fro;   // uniform -> s_load
                const float* fI = fhp + k * 136 + fio;
                float cr = 0.f, ci = 0.f;
#pragma unroll
                for (int i = 0; i < 17; ++i) {
                    cr = fmaf(fR[i], v[i], cr);
                    ci = fmaf(fI[i], v[i], ci);
                }
                bufB[p * CSTR + tsw] = cr;
                bufB[p * CSTR + 300 + tsw] = ci;
            }
        };
        doC(((wave & 3) << 6) + lane);               // t 0..255
        if (lane < 9 && (wave == 0 || wave == 4))
            doC(256 + lane);                         // t 256..264
    }
    __syncthreads();

    // ---- out phase: 6 conv-sets per channel; pairs get 2 outputs ----
    int nout = paired ? 384 : 192;
    if (tid < nout) {
        int chsel = paired ? (tid >= 192) : 0;
        int t3 = tid - chsel * 192;
        int s = t3 >> 5, X = t3 & 31;
        int kdist = (s < 3) ? s : s + 2;             // {0,1,2,5,6,7}
        int p = chsel * 6 + s;
        const float* hb = fhp + kdist * 136 + ((X == 0) ? 34 : 0);
        const float* cR = bufB + p * CSTR + 9 * X;
        float u = 0.f, v2 = 0.f;
#pragma unroll
        for (int j = 0; j < 17; ++j) {
            int off = j + (j >> 3);
            u  = fmaf(hb[j], cR[off], u);
            v2 = fmaf(hb[17 + j], cR[off + 300], v2);
        }
        int g = chsel ? gb : ga;
        int ch0 = isimg ? 1 : 11 + g * 10;
        out[nb + (size_t)(ch0 + kdist) * 1024 + Y * 32 + X] = u - v2;
        if (s == 1 || s == 2 || s == 4 || s == 5) {
            int partner = (s < 3) ? 5 - s : 13 - s;  // 4,3,9,8
            out[nb + (size_t)(ch0 + partner) * 1024 + Y * 32 + X] = u + v2;
        }
    } else if (isimg && tid < 224) {                 // s0: clipped 7x7 blur
        int X = tid - 192;
        float s0 = 0.f;
#pragma unroll
        for (int p = 0; p < 7; ++p)
#pragma unroll
            for (int q = 0; q < 7; ++q) {
                int c = 8 * X + q + 5;
                s0 = fmaf(blur[p * 7 + q], bufA[(p + 5) * W1 + c + (c >> 3)], s0);
            }
        out[nb + Y * 32 + X] = s0;
    }
}

extern "C" void kernel_launch(void* const* d_in, const int* in_sizes, int n_in,
                              void* d_out, int out_size, void* d_ws, size_t ws_size,
                              hipStream_t stream) {
    const float* img    = (const float*)d_in[0];
    const float* psi_re = (const float*)d_in[1];
    const float* psi_im = (const float*)d_in[2];
    const float* blur   = (const float*)d_in[3];
    float* out = (float*)d_out;
    float* ws = (float*)d_ws;
    float* pimg = ws;
    float* fhp  = ws + FHP_OFF;

    k_prep<<<289, 256, 0, stream>>>(img, psi_re, psi_im, blur, pimg, fhp);

    dim3 g2(32, 7, 8);
    k_fused4<<<g2, 512, 0, stream>>>(pimg, psi_re, psi_im, blur, fhp, out);
}